// Round 9
// baseline (1129.309 us; speedup 1.0000x reference)
//
#include <hip/hip_runtime.h>
#include <hip/hip_bf16.h>
#include <stdint.h>

// ---------------------------------------------------------------------------
// CapsuleNet forward, MI355X gfx950.  Round 9:
//  * conv2: R8's LDS-staged GEMM but NO ATOMICS -- S=2 split, each split
//    plain-stores bf16 partials to its own part buffer (R5/R7/R8 all
//    converged at ~413-493us because 18.9M device-scope atomicAdds were the
//    wall: R8's WRITE_SIZE=1.04GB ~= 18.9M x 64B write-through).
//  * k_caps2 sums the two partials + bias + squash.
//  * k_prep2: Wdb2 repack now coalesced (16-i-row chunks -> LDS -> 256B writes).
//  * h2f zeroing dropped (plain stores cover every cell).
// ---------------------------------------------------------------------------

typedef short short8 __attribute__((ext_vector_type(8)));
typedef unsigned short u16x8 __attribute__((ext_vector_type(8)));
typedef float f32x4  __attribute__((ext_vector_type(4)));

__device__ inline float bf2f(unsigned short u) {
    unsigned int v = ((unsigned int)u) << 16;
    float f;
    __builtin_memcpy(&f, &v, 4);
    return f;
}
__device__ inline unsigned short f2bf(float f) {
    __hip_bfloat16 h = __float2bfloat16(f);
    unsigned short u;
    __builtin_memcpy(&u, &h, 2);
    return u;
}
__device__ inline float clampf(float x, float b) {   // scrubs NaN -> -b
    return fminf(fmaxf(x, -b), b);
}
__device__ inline float rdf(const void* p, size_t i, int f) {
    return f ? ((const float*)p)[i] : bf2f(((const unsigned short*)p)[i]);
}
// fp32-vs-bf16 input detector (wave-uniform, ~512B of L2-hot reads)
__device__ inline int detect_f(const void* w1c) {
    const unsigned short* w = (const unsigned short*)w1c;
    int lane = threadIdx.x & 63;
    int cnt = 0;
#pragma unroll
    for (int j = 0; j < 4; ++j) {
        float v = fabsf(bf2f(w[lane * 4 + j]));
        if (v > 100.f) cnt++;
    }
#pragma unroll
    for (int off = 32; off; off >>= 1) cnt += __shfl_xor(cnt, off);
    return cnt >= 4;
}

// ---------------------------------------------------------------------------
// prep: repack conv1_w (blocks 0..95), pconv_w -> Bp3[t][kc][co][ci64] (96..351)
__global__ __launch_bounds__(256) void k_prep(
        const void* __restrict__ w1c, const void* __restrict__ w2c,
        unsigned short* __restrict__ B1p, unsigned short* __restrict__ Bp3) {
    __shared__ unsigned short wl[20736];           // [ci][t]
    int blk = blockIdx.x, tid = threadIdx.x;
    int f = detect_f(w1c);
    if (blk < 96) {
        int idx = blk * 256 + tid;                 // 256*96
        int co = idx / 96, k = idx - co * 96;
        B1p[idx] = (k < 81) ? f2bf(rdf(w1c, (size_t)co * 81 + k, f)) : (unsigned short)0;
    } else {
        int co = blk - 96;
        size_t base = (size_t)co * 20736;
        for (int i = tid; i < 20736; i += 256)
            wl[i] = f2bf(rdf(w2c, base + i, f));   // wl[ci*81+t]
        __syncthreads();
        for (int idx = tid; idx < 20736; idx += 256) {
            int t = idx >> 8, ci = idx & 255;      // 81*256
            int kc = ci >> 6, cin = ci & 63;
            Bp3[((size_t)(t * 4 + kc) << 14) + (co << 6) + cin] = wl[ci * 81 + t];
        }
    }
}

// prep2 (after conv2; targets overlay dead h1p region):
//   blocks 0..71   : W_dig -> Wdb2[o][n][i][8], coalesced read, LDS transpose
//   blocks 72..2119: dec_w2 cast -> w2b
//   blocks 2120..  : dec_w3 cast -> w3b (padded to 917504)
__global__ __launch_bounds__(256) void k_prep2(
        const void* __restrict__ wdig, const void* __restrict__ dw2,
        const void* __restrict__ dw3, const void* __restrict__ w1c,
        unsigned short* __restrict__ Wdb2,
        unsigned short* __restrict__ w2b,
        unsigned short* __restrict__ w3b) {
    __shared__ unsigned short wl[20480];           // 16 i-rows x 1280
    int f = detect_f(w1c);
    int blk = blockIdx.x, tid = threadIdx.x;
    if (blk < 72) {
        int i0 = blk * 16;
        size_t base = (size_t)i0 * 1280;
        for (int idx = tid; idx < 20480; idx += 256)
            wl[idx] = f2bf(rdf(wdig, base + idx, f));
        __syncthreads();
        if (tid < 160) {                           // (o,n) pair per thread
            int o = tid / 16, n = tid - o * 16;
            unsigned short* dst = Wdb2 + (size_t)o * 147456 + n * 9216 + i0 * 8;
            const unsigned short* src = wl + tid * 8;
#pragma unroll
            for (int i = 0; i < 16; ++i)
                *(uint4*)(dst + i * 8) = *(const uint4*)(src + i * 1280);
        }
    } else if (blk < 2120) {
        int idx = (blk - 72) * 256 + tid;          // 524,288
        w2b[idx] = f2bf(rdf(dw2, idx, f));
    } else {
        int idx = (blk - 2120) * 256 + tid;        // 917,504 (pad past 802,816)
        w3b[idx] = (idx < 802816) ? f2bf(rdf(dw3, idx, f)) : (unsigned short)0;
    }
}

// ---------------------------------------------------------------------------
// conv1: C[102400,256] = im2col(x) * B1p^T, 128x128 tiles, x staged in LDS.
__global__ __launch_bounds__(256) void k_conv1(
        const void* __restrict__ x,
        const unsigned short* __restrict__ B1p,
        const void* __restrict__ bias,
        unsigned short* __restrict__ h1p,
        const void* __restrict__ w1c) {
    __shared__ unsigned short xl[1568];            // up to 2 images, bf16
    __shared__ int offt[96];
    int f = detect_f(w1c);
    int tid = threadIdx.x;
    if (tid < 96) offt[tid] = (tid < 81) ? (tid / 9) * 28 + (tid % 9) : 0;

    int mblk = blockIdx.x * 128;
    int bfirst = mblk / 400;
    int blast = (mblk + 127) / 400;
    int nload = (blast - bfirst + 1) * 784;
    for (int i = tid; i < nload; i += 256)
        xl[i] = f2bf(rdf(x, (size_t)bfirst * 784 + i, f));
    __syncthreads();

    int wave = tid >> 6, lane = tid & 63;
    int wr = wave >> 1, wc = wave & 1;
    int mbase = mblk + wr * 64;
    int nbase = blockIdx.y * 128 + wc * 64;
    int l15 = lane & 15, l4 = lane >> 4;

    int lbase[4];
#pragma unroll
    for (int mt = 0; mt < 4; ++mt) {
        int m = mbase + mt * 16 + l15;
        int img = m / 400 - bfirst, pos = m % 400;
        lbase[mt] = img * 784 + (pos / 20) * 28 + (pos % 20);
    }

    f32x4 acc[4][4];
#pragma unroll
    for (int mt = 0; mt < 4; ++mt)
#pragma unroll
        for (int nt = 0; nt < 4; ++nt)
            acc[mt][nt] = (f32x4){0.f, 0.f, 0.f, 0.f};

#pragma unroll
    for (int kc = 0; kc < 3; ++kc) {
        int kbase = kc * 32 + l4 * 8;
        short8 af[4], bfr[4];
#pragma unroll
        for (int mt = 0; mt < 4; ++mt)
#pragma unroll
            for (int j = 0; j < 8; ++j) {
                int k = kbase + j;
                af[mt][j] = (k < 81) ? (short)xl[lbase[mt] + offt[k]] : (short)0;
            }
#pragma unroll
        for (int nt = 0; nt < 4; ++nt)
            bfr[nt] = *(const short8*)(B1p + (size_t)(nbase + nt * 16 + l15) * 96 + kbase);
#pragma unroll
        for (int mt = 0; mt < 4; ++mt)
#pragma unroll
            for (int nt = 0; nt < 4; ++nt)
                acc[mt][nt] = __builtin_amdgcn_mfma_f32_16x16x32_bf16(
                    af[mt], bfr[nt], acc[mt][nt], 0, 0, 0);
    }

#pragma unroll
    for (int mt = 0; mt < 4; ++mt)
#pragma unroll
        for (int nt = 0; nt < 4; ++nt) {
            int col = nbase + nt * 16 + l15;
            float bv = rdf(bias, col, f);
#pragma unroll
            for (int r = 0; r < 4; ++r) {
                int row = mbase + mt * 16 + l4 * 4 + r;
                h1p[(size_t)row * 256 + col] = f2bf(clampf(acc[mt][nt][r] + bv, 1024.f));
            }
        }
}

// ---------------------------------------------------------------------------
// conv2: LDS-staged implicit-im2col GEMM. 128x128 tile, BK=64, S=2 tap split.
// Padded LDS (stride 72 elems -> <=2-way). Staging line-perfect. Epilogue:
// PLAIN bf16 stores to part[s][row][col] (no atomics -- each cell once).
__global__ __launch_bounds__(256) void k_conv2(
        const unsigned short* __restrict__ h1p,
        const unsigned short* __restrict__ Bp,
        unsigned short* __restrict__ part) {
    __shared__ unsigned short As[9216];            // [128][72] bf16
    __shared__ unsigned short Bs[9216];
    int tid = threadIdx.x;
    int wave = tid >> 6, lane = tid & 63;
    int wr = wave >> 1, wc = wave & 1;
    int mb = blockIdx.x * 128, nb = blockIdx.y * 128;
    int s = blockIdx.z;
    int t0 = (81 * s) >> 1, t1 = (81 * (s + 1)) >> 1;
    int l15 = lane & 15, l4 = lane >> 4;

    int seg = tid & 7;
    int arow_off[4];
#pragma unroll
    for (int p = 0; p < 4; ++p) {
        int r = p * 32 + (tid >> 3);
        int m = mb + r;
        int bb = m / 36, pos = m - bb * 36;
        int y = pos / 6, xx = pos - y * 6;
        arow_off[p] = (bb * 400 + y * 40 + xx * 2) * 256 + seg * 8;
    }
    unsigned short* aw = As + (tid >> 3) * 72 + seg * 8;
    unsigned short* bw = Bs + (tid >> 3) * 72 + seg * 8;

    int arow[4], brow[4];
#pragma unroll
    for (int mt = 0; mt < 4; ++mt) arow[mt] = (wr * 64 + mt * 16 + l15) * 72;
#pragma unroll
    for (int nt = 0; nt < 4; ++nt) brow[nt] = (wc * 64 + nt * 16 + l15) * 72;

    f32x4 acc[4][4];
#pragma unroll
    for (int mt = 0; mt < 4; ++mt)
#pragma unroll
        for (int nt = 0; nt < 4; ++nt)
            acc[mt][nt] = (f32x4){0.f, 0.f, 0.f, 0.f};

    for (int t = t0; t < t1; ++t) {
        int ky = t / 9, kx = t - ky * 9;
        int tadd = (ky * 20 + kx) * 256;
#pragma unroll
        for (int kc = 0; kc < 4; ++kc) {
            const unsigned short* bbase =
                Bp + (((size_t)(t * 4 + kc)) << 14) + nb * 64;
            uint4 av[4], bv[4];
#pragma unroll
            for (int p = 0; p < 4; ++p) {
                av[p] = *(const uint4*)(h1p + arow_off[p] + tadd + kc * 64);
                bv[p] = *(const uint4*)(bbase + (p << 11) + (tid << 3));
            }
            __syncthreads();
#pragma unroll
            for (int p = 0; p < 4; ++p) {
                *(uint4*)(aw + p * 2304) = av[p];
                *(uint4*)(bw + p * 2304) = bv[p];
            }
            __syncthreads();
#pragma unroll
            for (int kk = 0; kk < 2; ++kk) {
                int ko = kk * 32 + l4 * 8;
                short8 af[4], bfr[4];
#pragma unroll
                for (int mt = 0; mt < 4; ++mt)
                    af[mt] = *(const short8*)(As + arow[mt] + ko);
#pragma unroll
                for (int nt = 0; nt < 4; ++nt)
                    bfr[nt] = *(const short8*)(Bs + brow[nt] + ko);
#pragma unroll
                for (int mt = 0; mt < 4; ++mt)
#pragma unroll
                    for (int nt = 0; nt < 4; ++nt)
                        acc[mt][nt] = __builtin_amdgcn_mfma_f32_16x16x32_bf16(
                            af[mt], bfr[nt], acc[mt][nt], 0, 0, 0);
            }
        }
    }

    unsigned short* outp = part + (size_t)s * 2359296;
#pragma unroll
    for (int mt = 0; mt < 4; ++mt)
#pragma unroll
        for (int nt = 0; nt < 4; ++nt) {
            int col = nb + wc * 64 + nt * 16 + l15;
#pragma unroll
            for (int r = 0; r < 4; ++r) {
                int row = mb + wr * 64 + mt * 16 + l4 * 4 + r;
                outp[(size_t)row * 256 + col] = f2bf(acc[mt][nt][r]);
            }
        }
}

// ---------------------------------------------------------------------------
// caps: one block per image. Sum 2 bf16 partials coalesced -> LDS -> squash.
__global__ __launch_bounds__(256) void k_caps2(
        const unsigned short* __restrict__ part, const void* __restrict__ pb,
        unsigned short* __restrict__ caps, const void* __restrict__ w1c) {
    __shared__ float ld[9216];                     // [pos 36][co 256]
    int f = detect_f(w1c);
    int b = blockIdx.x, tid = threadIdx.x;
#pragma unroll 4
    for (int p = 0; p < 36; ++p) {
        size_t off = (size_t)b * 9216 + p * 256 + tid;
        ld[p * 256 + tid] = bf2f(part[off]) + bf2f(part[2359296 + off]);
    }
    __syncthreads();
    for (int c = tid; c < 1152; c += 256) {
        float h[8], ss = 0.f;
#pragma unroll
        for (int d = 0; d < 8; ++d) {
            int flat = c * 8 + d;                  // = co*36 + pos
            int co = flat / 36, pos = flat - co * 36;
            float v = clampf(ld[pos * 256 + co] + rdf(pb, co, f), 20000.f);
            h[d] = v;
            ss += v * v;
        }
        float sc = sqrtf(ss) / (1.f + ss);
        u16x8 cv;
#pragma unroll
        for (int d = 0; d < 8; ++d) cv[d] = f2bf(h[d] * sc);
        *(u16x8*)(caps + ((size_t)b * 1152 + c) * 8) = cv;
    }
}

// ---------------------------------------------------------------------------
// Dynamic routing. One block per (b,o). u[1152][16] in registers, 3 rows/thr.
__global__ __launch_bounds__(384) void k_routing(
        const unsigned short* __restrict__ caps, const unsigned short* __restrict__ Wdb2,
        const int* __restrict__ label, void* __restrict__ d_out,
        float* __restrict__ vsel, const void* __restrict__ w1c) {
    int f = detect_f(w1c);
    int bo = blockIdx.x;
    int b = bo / 10, o = bo - b * 10;
    int tid = threadIdx.x;
    int wid = tid >> 6, lane = tid & 63;

    __shared__ float redw[6][16];
    __shared__ float sbuf[16];
    __shared__ float mred[8];
    __shared__ float sred[8];

    float u[3][16];
    float a[3] = {0.f, 0.f, 0.f};
    const unsigned short* capb = caps + (size_t)b * 9216;
    const unsigned short* wob = Wdb2 + (size_t)o * 147456;

#pragma unroll
    for (int r = 0; r < 3; ++r) {
        int i = tid + r * 384;                       // covers 0..1151 exactly
        u16x8 cq = *(const u16x8*)(capb + i * 8);
        float cf[8];
#pragma unroll
        for (int d = 0; d < 8; ++d) cf[d] = clampf(bf2f(cq[d]), 100.f);
#pragma unroll
        for (int n = 0; n < 16; ++n) {
            u16x8 q = *(const u16x8*)(wob + ((size_t)n * 1152 + i) * 8);
            float sacc = 0.f;
#pragma unroll
            for (int d = 0; d < 8; ++d) sacc += clampf(bf2f(q[d]), 1000.f) * cf[d];
            u[r][n] = clampf(sacc, 1.0e6f);
        }
    }

    for (int rr = 1; rr <= 3; ++rr) {
        float mx = fmaxf(fmaxf(a[0], a[1]), a[2]);
#pragma unroll
        for (int off = 32; off; off >>= 1) mx = fmaxf(mx, __shfl_xor(mx, off));
        if (lane == 0) mred[wid] = mx;
        __syncthreads();
        float M = mred[0];
#pragma unroll
        for (int w = 1; w < 6; ++w) M = fmaxf(M, mred[w]);

        float e[3], es = 0.f;
#pragma unroll
        for (int r = 0; r < 3; ++r) { e[r] = __expf(a[r] - M); es += e[r]; }
#pragma unroll
        for (int off = 32; off; off >>= 1) es += __shfl_xor(es, off);
        if (lane == 0) sred[wid] = es;
        __syncthreads();
        float S = 0.f;
#pragma unroll
        for (int w = 0; w < 6; ++w) S += sred[w];
        float inv = 1.f / S;

        float p[16];
#pragma unroll
        for (int n = 0; n < 16; ++n)
            p[n] = (e[0] * u[0][n] + e[1] * u[1][n] + e[2] * u[2][n]) * inv;
#pragma unroll
        for (int n = 0; n < 16; ++n)
#pragma unroll
            for (int off = 32; off; off >>= 1) p[n] += __shfl_xor(p[n], off);
        if (lane == 0)
#pragma unroll
            for (int n = 0; n < 16; ++n) redw[wid][n] = p[n];
        __syncthreads();
        if (tid < 16) {
            float sn = 0.f;
#pragma unroll
            for (int w = 0; w < 6; ++w) sn += redw[w][tid];
            sbuf[tid] = clampf(sn, 3.0e9f);
        }
        __syncthreads();

        float ss = 0.f;
#pragma unroll
        for (int n = 0; n < 16; ++n) ss += sbuf[n] * sbuf[n];
        float sc = sqrtf(ss) / (1.f + ss);

        if (rr < 3) {
#pragma unroll
            for (int r = 0; r < 3; ++r) {
                float dot = 0.f;
#pragma unroll
                for (int n = 0; n < 16; ++n) dot += sbuf[n] * u[r][n];
                a[r] += sc * dot;
            }
            __syncthreads();
        } else {
            int lbl = label[b];
            if (tid < 16) {
                float vn = clampf(sbuf[tid] * sc, 1.f);
                if (f) ((float*)d_out)[(bo << 4) + tid] = vn;
                else   ((unsigned short*)d_out)[(bo << 4) + tid] = f2bf(vn);
                if (o == lbl) vsel[(b << 4) + tid] = vn;
            }
            if (tid == 0) {
                float oh = (o == lbl) ? 1.f : 0.f;
                if (f) ((float*)d_out)[241664 + bo] = oh;
                else   ((unsigned short*)d_out)[241664 + bo] = f2bf(oh);
            }
        }
    }
}

// ---------------------------------------------------------------------------
// decoder layer 1 (K=16, masked): r1b bf16 [256][512]
__global__ void k_dec1(const float* __restrict__ vsel, const int* __restrict__ label,
                       const void* __restrict__ w1, const void* __restrict__ b1,
                       unsigned short* __restrict__ r1b, const void* __restrict__ w1c) {
    int f = detect_f(w1c);
    int b = blockIdx.x, j = threadIdx.x;   // 512 threads
    __shared__ float vs[16];
    if (j < 16) vs[j] = vsel[b * 16 + j];
    __syncthreads();
    int lbl = label[b];
    size_t wb = (size_t)j * 160 + lbl * 16;
    float acc = rdf(b1, j, f);
#pragma unroll
    for (int n = 0; n < 16; ++n) acc += rdf(w1, wb + n, f) * vs[n];
    r1b[b * 512 + j] = f2bf(fmaxf(acc, 0.f));
}

// decoder GEMM: C[256,N] = A[256,K] x B[N,K]^T (+bias, act). 128x128 tiles.
__global__ __launch_bounds__(256) void k_dgemm(
        const unsigned short* __restrict__ A, const unsigned short* __restrict__ B,
        const void* __restrict__ bias, int K, int mode, int nvalid, int ostride,
        unsigned short* __restrict__ outb, void* __restrict__ d_out,
        const void* __restrict__ w1c) {
    int f = detect_f(w1c);
    int tid = threadIdx.x;
    int wave = tid >> 6, lane = tid & 63;
    int wr = wave >> 1, wc = wave & 1;
    int mbase = blockIdx.x * 128 + wr * 64;
    int nbase = blockIdx.y * 128 + wc * 64;
    int l15 = lane & 15, l4 = lane >> 4;
    int koff = l4 * 8;

    f32x4 acc[4][4];
#pragma unroll
    for (int mt = 0; mt < 4; ++mt)
#pragma unroll
        for (int nt = 0; nt < 4; ++nt)
            acc[mt][nt] = (f32x4){0.f, 0.f, 0.f, 0.f};

    int nch = K >> 5;
    for (int kc = 0; kc < nch; ++kc) {
        int k0 = kc * 32 + koff;
        short8 af[4], bfr[4];
#pragma unroll
        for (int mt = 0; mt < 4; ++mt)
            af[mt] = *(const short8*)(A + (size_t)(mbase + mt * 16 + l15) * K + k0);
#pragma unroll
        for (int nt = 0; nt < 4; ++nt)
            bfr[nt] = *(const short8*)(B + (size_t)(nbase + nt * 16 + l15) * K + k0);
#pragma unroll
        for (int mt = 0; mt < 4; ++mt)
#pragma unroll
            for (int nt = 0; nt < 4; ++nt)
                acc[mt][nt] = __builtin_amdgcn_mfma_f32_16x16x32_bf16(
                    af[mt], bfr[nt], acc[mt][nt], 0, 0, 0);
    }

#pragma unroll
    for (int mt = 0; mt < 4; ++mt)
#pragma unroll
        for (int nt = 0; nt < 4; ++nt) {
            int col = nbase + nt * 16 + l15;
            float bv = (col < nvalid) ? rdf(bias, col, f) : 0.f;
#pragma unroll
            for (int r = 0; r < 4; ++r) {
                int row = mbase + mt * 16 + l4 * 4 + r;
                float v = acc[mt][nt][r] + bv;
                if (mode == 0) {
                    outb[(size_t)row * ostride + col] = f2bf(fmaxf(v, 0.f));
                } else if (col < nvalid) {
                    float a = clampf(v, 60.f);
                    float sig = 1.f / (1.f + __expf(-a));
                    size_t oi = 40960 + (size_t)row * 784 + col;
                    if (f) ((float*)d_out)[oi] = sig;
                    else   ((unsigned short*)d_out)[oi] = f2bf(sig);
                }
            }
        }
}

// ---------------------------------------------------------------------------
extern "C" void kernel_launch(void* const* d_in, const int* in_sizes, int n_in,
                              void* d_out, int out_size, void* d_ws, size_t ws_size,
                              hipStream_t stream) {
    const void* x    = d_in[0];
    const int*  lbl  = (const int*)d_in[1];
    const void* w1c  = d_in[2];
    const void* b1c  = d_in[3];
    const void* w2c  = d_in[4];
    const void* b2c  = d_in[5];
    const void* wdig = d_in[6];
    const void* dw1  = d_in[7];
    const void* db1  = d_in[8];
    const void* dw2  = d_in[9];
    const void* db2  = d_in[10];
    const void* dw3  = d_in[11];
    const void* db3  = d_in[12];
    (void)in_sizes; (void)n_in; (void)out_size; (void)ws_size;

    char* ws = (char*)d_ws;
    // ---- layout, total 72,531,968 B (ws_size >= 74,123,264 known from R4) --
    unsigned short* part = (unsigned short*)(ws);             // 2 x 4,718,592
    unsigned short* Bp3  = (unsigned short*)(ws + 9437184);   // 10,616,832 [dead after conv2]
    unsigned short* caps = (unsigned short*)(ws + 9437184);   //   overlay: 4,718,592
    unsigned short* B1p  = (unsigned short*)(ws + 20054016);  // 49,152
    unsigned short* h1p  = (unsigned short*)(ws + 20103168);  // 52,428,800 [dead after conv2]
    //   overlays inside h1p region (written after conv2 by k_prep2 etc):
    unsigned short* Wdb2 = (unsigned short*)(ws + 20103168);  // 2,949,120
    unsigned short* w2b  = (unsigned short*)(ws + 23052288);  // 1,048,576
    unsigned short* w3b  = (unsigned short*)(ws + 24100864);  // 1,835,008
    unsigned short* r1b  = (unsigned short*)(ws + 25935872);  // 262,144
    unsigned short* r2b  = (unsigned short*)(ws + 26198016);  // 524,288
    float* vsel          = (float*)(ws + 26722304);           // 16,384

    hipLaunchKernelGGL(k_prep,  dim3(352),      dim3(256), 0, stream, w1c, w2c, B1p, Bp3);
    hipLaunchKernelGGL(k_conv1, dim3(800, 2),   dim3(256), 0, stream, x, B1p, b1c, h1p, w1c);
    hipLaunchKernelGGL(k_conv2, dim3(72, 2, 2), dim3(256), 0, stream, h1p, Bp3, part);
    hipLaunchKernelGGL(k_prep2, dim3(5704),     dim3(256), 0, stream,
                       wdig, dw2, dw3, w1c, Wdb2, w2b, w3b);
    hipLaunchKernelGGL(k_caps2, dim3(256),      dim3(256), 0, stream, part, b2c, caps, w1c);
    hipLaunchKernelGGL(k_routing, dim3(2560),   dim3(384), 0, stream, caps, Wdb2, lbl,
                       d_out, vsel, w1c);
    hipLaunchKernelGGL(k_dec1,  dim3(256),      dim3(512), 0, stream, vsel, lbl, dw1, db1, r1b, w1c);
    hipLaunchKernelGGL(k_dgemm, dim3(2, 8),     dim3(256), 0, stream,
                       r1b, w2b, db2, 512, 0, 1024, 1024, r2b, d_out, w1c);
    hipLaunchKernelGGL(k_dgemm, dim3(2, 7),     dim3(256), 0, stream,
                       r2b, w3b, db3, 1024, 1, 784, 0, (unsigned short*)nullptr, d_out, w1c);
}

// Round 10
// 561.619 us; speedup vs baseline: 2.0108x; 2.0108x over previous
//
#include <hip/hip_runtime.h>
#include <hip/hip_bf16.h>
#include <stdint.h>

// ---------------------------------------------------------------------------
// CapsuleNet forward, MI355X gfx950.  Round 10:
//  * conv2: m97-faithful LDS GEMM -- 128x128 tile, BK=64, UNPADDED [128][64]
//    LDS, ALL staging via async global_load_lds(16B) (no VGPR round-trip, no
//    pre-ds_write vmcnt drain), single-buffered, 2 barriers/chunk, S=8 split,
//    contiguous fp32 atomics (R5-proven 4B-effective) into zeroed h2f.
//    R8/R9 failed on manual-staging barrier drains (0.05-0.08 lines/cyc/CU
//    vs direct 0.19); async DMA is the m93->m97 2.4x step.
//  * routing: hot-loop clamps removed (finite data proven over 6 passes).
// ---------------------------------------------------------------------------

typedef short short8 __attribute__((ext_vector_type(8)));
typedef unsigned short u16x8 __attribute__((ext_vector_type(8)));
typedef float f32x4  __attribute__((ext_vector_type(4)));

__device__ inline float bf2f(unsigned short u) {
    unsigned int v = ((unsigned int)u) << 16;
    float f;
    __builtin_memcpy(&f, &v, 4);
    return f;
}
__device__ inline unsigned short f2bf(float f) {
    __hip_bfloat16 h = __float2bfloat16(f);
    unsigned short u;
    __builtin_memcpy(&u, &h, 2);
    return u;
}
__device__ inline float clampf(float x, float b) {   // scrubs NaN -> -b
    return fminf(fmaxf(x, -b), b);
}
__device__ inline float rdf(const void* p, size_t i, int f) {
    return f ? ((const float*)p)[i] : bf2f(((const unsigned short*)p)[i]);
}
__device__ inline void gload_lds16(const unsigned short* g, unsigned short* l) {
    __builtin_amdgcn_global_load_lds(
        (const __attribute__((address_space(1))) void*)g,
        (__attribute__((address_space(3))) void*)l, 16, 0, 0);
}
// fp32-vs-bf16 input detector (wave-uniform)
__device__ inline int detect_f(const void* w1c) {
    const unsigned short* w = (const unsigned short*)w1c;
    int lane = threadIdx.x & 63;
    int cnt = 0;
#pragma unroll
    for (int j = 0; j < 4; ++j) {
        float v = fabsf(bf2f(w[lane * 4 + j]));
        if (v > 100.f) cnt++;
    }
#pragma unroll
    for (int off = 32; off; off >>= 1) cnt += __shfl_xor(cnt, off);
    return cnt >= 4;
}

// ---------------------------------------------------------------------------
// prep: zero h2f (blocks 0..2303), repack conv1_w (2304..2399),
//       pconv_w -> Bp3[t*4+kc][co][ci64] (2400..2655, one block per co)
__global__ __launch_bounds__(256) void k_prep(
        const void* __restrict__ w1c, const void* __restrict__ w2c,
        float* __restrict__ h2f, unsigned short* __restrict__ B1p,
        unsigned short* __restrict__ Bp3) {
    __shared__ unsigned short wl[20736];           // [ci][t]
    int blk = blockIdx.x, tid = threadIdx.x;
    if (blk < 2304) {
        ((f32x4*)h2f)[blk * 256 + tid] = (f32x4){0.f, 0.f, 0.f, 0.f};
    } else if (blk < 2400) {
        int f = detect_f(w1c);
        int idx = (blk - 2304) * 256 + tid;        // 256*96
        int co = idx / 96, k = idx - co * 96;
        B1p[idx] = (k < 81) ? f2bf(rdf(w1c, (size_t)co * 81 + k, f)) : (unsigned short)0;
    } else {
        int f = detect_f(w1c);
        int co = blk - 2400;
        size_t base = (size_t)co * 20736;
        for (int i = tid; i < 20736; i += 256)
            wl[i] = f2bf(rdf(w2c, base + i, f));   // wl[ci*81+t]
        __syncthreads();
        for (int idx = tid; idx < 20736; idx += 256) {
            int t = idx >> 8, ci = idx & 255;      // 81*256
            int kc = ci >> 6, cin = ci & 63;
            Bp3[((size_t)(t * 4 + kc) << 14) + (co << 6) + cin] = wl[ci * 81 + t];
        }
    }
}

// prep2 (after conv2; overlays dead h1p region):
//   blocks 0..71: W_dig -> Wdb2[o][n][i][8] (coalesced, LDS transpose)
//   72..2119: dec_w2 cast; rest: dec_w3 cast (padded)
__global__ __launch_bounds__(256) void k_prep2(
        const void* __restrict__ wdig, const void* __restrict__ dw2,
        const void* __restrict__ dw3, const void* __restrict__ w1c,
        unsigned short* __restrict__ Wdb2,
        unsigned short* __restrict__ w2b,
        unsigned short* __restrict__ w3b) {
    __shared__ unsigned short wl[20480];           // 16 i-rows x 1280
    int f = detect_f(w1c);
    int blk = blockIdx.x, tid = threadIdx.x;
    if (blk < 72) {
        int i0 = blk * 16;
        size_t base = (size_t)i0 * 1280;
        for (int idx = tid; idx < 20480; idx += 256)
            wl[idx] = f2bf(rdf(wdig, base + idx, f));
        __syncthreads();
        if (tid < 160) {                           // (o,n) pair per thread
            int o = tid / 16, n = tid - o * 16;
            unsigned short* dst = Wdb2 + (size_t)o * 147456 + n * 9216 + i0 * 8;
            const unsigned short* src = wl + tid * 8;
#pragma unroll
            for (int i = 0; i < 16; ++i)
                *(uint4*)(dst + i * 8) = *(const uint4*)(src + i * 1280);
        }
    } else if (blk < 2120) {
        int idx = (blk - 72) * 256 + tid;          // 524,288
        w2b[idx] = f2bf(rdf(dw2, idx, f));
    } else {
        int idx = (blk - 2120) * 256 + tid;        // 917,504 (pad past 802,816)
        w3b[idx] = (idx < 802816) ? f2bf(rdf(dw3, idx, f)) : (unsigned short)0;
    }
}

// ---------------------------------------------------------------------------
// conv1: C[102400,256] = im2col(x) * B1p^T, 128x128 tiles, x staged in LDS.
__global__ __launch_bounds__(256) void k_conv1(
        const void* __restrict__ x,
        const unsigned short* __restrict__ B1p,
        const void* __restrict__ bias,
        unsigned short* __restrict__ h1p,
        const void* __restrict__ w1c) {
    __shared__ unsigned short xl[1568];            // up to 2 images, bf16
    __shared__ int offt[96];
    int f = detect_f(w1c);
    int tid = threadIdx.x;
    if (tid < 96) offt[tid] = (tid < 81) ? (tid / 9) * 28 + (tid % 9) : 0;

    int mblk = blockIdx.x * 128;
    int bfirst = mblk / 400;
    int blast = (mblk + 127) / 400;
    int nload = (blast - bfirst + 1) * 784;
    for (int i = tid; i < nload; i += 256)
        xl[i] = f2bf(rdf(x, (size_t)bfirst * 784 + i, f));
    __syncthreads();

    int wave = tid >> 6, lane = tid & 63;
    int wr = wave >> 1, wc = wave & 1;
    int mbase = mblk + wr * 64;
    int nbase = blockIdx.y * 128 + wc * 64;
    int l15 = lane & 15, l4 = lane >> 4;

    int lbase[4];
#pragma unroll
    for (int mt = 0; mt < 4; ++mt) {
        int m = mbase + mt * 16 + l15;
        int img = m / 400 - bfirst, pos = m % 400;
        lbase[mt] = img * 784 + (pos / 20) * 28 + (pos % 20);
    }

    f32x4 acc[4][4];
#pragma unroll
    for (int mt = 0; mt < 4; ++mt)
#pragma unroll
        for (int nt = 0; nt < 4; ++nt)
            acc[mt][nt] = (f32x4){0.f, 0.f, 0.f, 0.f};

#pragma unroll
    for (int kc = 0; kc < 3; ++kc) {
        int kbase = kc * 32 + l4 * 8;
        short8 af[4], bfr[4];
#pragma unroll
        for (int mt = 0; mt < 4; ++mt)
#pragma unroll
            for (int j = 0; j < 8; ++j) {
                int k = kbase + j;
                af[mt][j] = (k < 81) ? (short)xl[lbase[mt] + offt[k]] : (short)0;
            }
#pragma unroll
        for (int nt = 0; nt < 4; ++nt)
            bfr[nt] = *(const short8*)(B1p + (size_t)(nbase + nt * 16 + l15) * 96 + kbase);
#pragma unroll
        for (int mt = 0; mt < 4; ++mt)
#pragma unroll
            for (int nt = 0; nt < 4; ++nt)
                acc[mt][nt] = __builtin_amdgcn_mfma_f32_16x16x32_bf16(
                    af[mt], bfr[nt], acc[mt][nt], 0, 0, 0);
    }

#pragma unroll
    for (int mt = 0; mt < 4; ++mt)
#pragma unroll
        for (int nt = 0; nt < 4; ++nt) {
            int col = nbase + nt * 16 + l15;
            float bv = rdf(bias, col, f);
#pragma unroll
            for (int r = 0; r < 4; ++r) {
                int row = mbase + mt * 16 + l4 * 4 + r;
                h1p[(size_t)row * 256 + col] = f2bf(clampf(acc[mt][nt][r] + bv, 1024.f));
            }
        }
}

// ---------------------------------------------------------------------------
// conv2: m97-style LDS GEMM. 128x128 tile, BK=64, S=8 tap split.
// Unpadded LDS [128][64]; staging = async global_load_lds(16B):
//   instr q = wave*4+r covers LDS bytes [q*1024, q*1024+1024) = rows q*8..+7.
//   A gptr per lane from im2col rowoff; B = linear copy of 16KB Bp3 window.
// Epilogue: contiguous fp32 atomicAdd into h2f[row][col].
__global__ __launch_bounds__(256) void k_conv2(
        const unsigned short* __restrict__ h1p,
        const unsigned short* __restrict__ Bp,
        float* __restrict__ h2f) {
    __shared__ unsigned short As[8192];            // [128][64] bf16, 16 KB
    __shared__ unsigned short Bs[8192];
    int tid = threadIdx.x;
    int wave = tid >> 6, lane = tid & 63;
    int wr = wave >> 1, wc = wave & 1;
    int mb = blockIdx.x * 128, nb = blockIdx.y * 128;
    int s = blockIdx.z;
    int t0 = (81 * s) >> 3, t1 = (81 * (s + 1)) >> 3;
    int l15 = lane & 15, l4 = lane >> 4;

    // A staging gptr components: round r -> row = wave*32 + r*8 + (lane>>3)
    int seg = lane & 7;
    int rsub = lane >> 3;
    int arowoff[4];
#pragma unroll
    for (int r = 0; r < 4; ++r) {
        int m = mb + wave * 32 + r * 8 + rsub;
        int bb = m / 36, pos = m - bb * 36;
        int y = pos / 6, xx = pos - y * 6;
        arowoff[r] = (bb * 400 + y * 40 + xx * 2) * 256 + seg * 8;
    }
    int lane8 = lane << 3;                         // B linear elem offset

    int arow[4], brow[4];
#pragma unroll
    for (int mt = 0; mt < 4; ++mt) arow[mt] = (wr * 64 + mt * 16 + l15) << 6;
#pragma unroll
    for (int nt = 0; nt < 4; ++nt) brow[nt] = (wc * 64 + nt * 16 + l15) << 6;

    f32x4 acc[4][4];
#pragma unroll
    for (int mt = 0; mt < 4; ++mt)
#pragma unroll
        for (int nt = 0; nt < 4; ++nt)
            acc[mt][nt] = (f32x4){0.f, 0.f, 0.f, 0.f};

    for (int t = t0; t < t1; ++t) {
        int ky = t / 9, kx = t - ky * 9;
        int tadd = (ky * 20 + kx) * 256;
#pragma unroll
        for (int kc = 0; kc < 4; ++kc) {
            const unsigned short* bwin =
                Bp + (((size_t)(t * 4 + kc)) << 14) + nb * 64;
#pragma unroll
            for (int r = 0; r < 4; ++r) {
                int q512 = (wave * 4 + r) << 9;    // q*512 elems
                gload_lds16(h1p + arowoff[r] + tadd + (kc << 6), As + q512);
                gload_lds16(bwin + q512 + lane8,                Bs + q512);
            }
            __syncthreads();
#pragma unroll
            for (int kk = 0; kk < 2; ++kk) {
                int ko = (kk << 5) + (l4 << 3);
                short8 af[4], bfr[4];
#pragma unroll
                for (int mt = 0; mt < 4; ++mt)
                    af[mt] = *(const short8*)(As + arow[mt] + ko);
#pragma unroll
                for (int nt = 0; nt < 4; ++nt)
                    bfr[nt] = *(const short8*)(Bs + brow[nt] + ko);
#pragma unroll
                for (int mt = 0; mt < 4; ++mt)
#pragma unroll
                    for (int nt = 0; nt < 4; ++nt)
                        acc[mt][nt] = __builtin_amdgcn_mfma_f32_16x16x32_bf16(
                            af[mt], bfr[nt], acc[mt][nt], 0, 0, 0);
            }
            __syncthreads();
        }
    }

#pragma unroll
    for (int mt = 0; mt < 4; ++mt)
#pragma unroll
        for (int nt = 0; nt < 4; ++nt) {
            int col = nb + wc * 64 + nt * 16 + l15;
#pragma unroll
            for (int r = 0; r < 4; ++r) {
                int row = mb + wr * 64 + mt * 16 + l4 * 4 + r;
                atomicAdd(&h2f[(size_t)row * 256 + col], acc[mt][nt][r]);
            }
        }
}

// ---------------------------------------------------------------------------
// caps: one block per image. Coalesced 36KB load -> LDS transpose -> squash.
__global__ __launch_bounds__(256) void k_caps2(
        const float* __restrict__ h2f, const void* __restrict__ pb,
        unsigned short* __restrict__ caps, const void* __restrict__ w1c) {
    __shared__ float ld[9216];                     // [pos 36][co 256]
    int f = detect_f(w1c);
    int b = blockIdx.x, tid = threadIdx.x;
#pragma unroll 4
    for (int p = 0; p < 36; ++p)
        ld[p * 256 + tid] = h2f[(size_t)b * 9216 + p * 256 + tid];
    __syncthreads();
    for (int c = tid; c < 1152; c += 256) {
        float h[8], ss = 0.f;
#pragma unroll
        for (int d = 0; d < 8; ++d) {
            int flat = c * 8 + d;                  // = co*36 + pos
            int co = flat / 36, pos = flat - co * 36;
            float v = clampf(ld[pos * 256 + co] + rdf(pb, co, f), 20000.f);
            h[d] = v;
            ss += v * v;
        }
        float sc = sqrtf(ss) / (1.f + ss);
        u16x8 cv;
#pragma unroll
        for (int d = 0; d < 8; ++d) cv[d] = f2bf(h[d] * sc);
        *(u16x8*)(caps + ((size_t)b * 1152 + c) * 8) = cv;
    }
}

// ---------------------------------------------------------------------------
// Dynamic routing. One block per (b,o). u[1152][16] in registers, 3 rows/thr.
// Hot loops clamp-free (data finite, proven R4-R9).
__global__ __launch_bounds__(384) void k_routing(
        const unsigned short* __restrict__ caps, const unsigned short* __restrict__ Wdb2,
        const int* __restrict__ label, void* __restrict__ d_out,
        float* __restrict__ vsel, const void* __restrict__ w1c) {
    int f = detect_f(w1c);
    int bo = blockIdx.x;
    int b = bo / 10, o = bo - b * 10;
    int tid = threadIdx.x;
    int wid = tid >> 6, lane = tid & 63;

    __shared__ float redw[6][16];
    __shared__ float sbuf[16];
    __shared__ float mred[8];
    __shared__ float sred[8];

    float u[3][16];
    float a[3] = {0.f, 0.f, 0.f};
    const unsigned short* capb = caps + (size_t)b * 9216;
    const unsigned short* wob = Wdb2 + (size_t)o * 147456;

#pragma unroll
    for (int r = 0; r < 3; ++r) {
        int i = tid + r * 384;                       // covers 0..1151 exactly
        u16x8 cq = *(const u16x8*)(capb + i * 8);
        float cf[8];
#pragma unroll
        for (int d = 0; d < 8; ++d) cf[d] = bf2f(cq[d]);
#pragma unroll
        for (int n = 0; n < 16; ++n) {
            u16x8 q = *(const u16x8*)(wob + ((size_t)n * 1152 + i) * 8);
            float sacc = 0.f;
#pragma unroll
            for (int d = 0; d < 8; ++d) sacc += bf2f(q[d]) * cf[d];
            u[r][n] = sacc;
        }
    }

    for (int rr = 1; rr <= 3; ++rr) {
        float mx = fmaxf(fmaxf(a[0], a[1]), a[2]);
#pragma unroll
        for (int off = 32; off; off >>= 1) mx = fmaxf(mx, __shfl_xor(mx, off));
        if (lane == 0) mred[wid] = mx;
        __syncthreads();
        float M = mred[0];
#pragma unroll
        for (int w = 1; w < 6; ++w) M = fmaxf(M, mred[w]);

        float e[3], es = 0.f;
#pragma unroll
        for (int r = 0; r < 3; ++r) { e[r] = __expf(a[r] - M); es += e[r]; }
#pragma unroll
        for (int off = 32; off; off >>= 1) es += __shfl_xor(es, off);
        if (lane == 0) sred[wid] = es;
        __syncthreads();
        float S = 0.f;
#pragma unroll
        for (int w = 0; w < 6; ++w) S += sred[w];
        float inv = 1.f / S;

        float p[16];
#pragma unroll
        for (int n = 0; n < 16; ++n)
            p[n] = (e[0] * u[0][n] + e[1] * u[1][n] + e[2] * u[2][n]) * inv;
#pragma unroll
        for (int n = 0; n < 16; ++n)
#pragma unroll
            for (int off = 32; off; off >>= 1) p[n] += __shfl_xor(p[n], off);
        if (lane == 0)
#pragma unroll
            for (int n = 0; n < 16; ++n) redw[wid][n] = p[n];
        __syncthreads();
        if (tid < 16) {
            float sn = 0.f;
#pragma unroll
            for (int w = 0; w < 6; ++w) sn += redw[w][tid];
            sbuf[tid] = sn;
        }
        __syncthreads();

        float ss = 0.f;
#pragma unroll
        for (int n = 0; n < 16; ++n) ss += sbuf[n] * sbuf[n];
        float sc = sqrtf(ss) / (1.f + ss);

        if (rr < 3) {
#pragma unroll
            for (int r = 0; r < 3; ++r) {
                float dot = 0.f;
#pragma unroll
                for (int n = 0; n < 16; ++n) dot += sbuf[n] * u[r][n];
                a[r] += sc * dot;
            }
            __syncthreads();
        } else {
            int lbl = label[b];
            if (tid < 16) {
                float vn = clampf(sbuf[tid] * sc, 1.f);
                if (f) ((float*)d_out)[(bo << 4) + tid] = vn;
                else   ((unsigned short*)d_out)[(bo << 4) + tid] = f2bf(vn);
                if (o == lbl) vsel[(b << 4) + tid] = vn;
            }
            if (tid == 0) {
                float oh = (o == lbl) ? 1.f : 0.f;
                if (f) ((float*)d_out)[241664 + bo] = oh;
                else   ((unsigned short*)d_out)[241664 + bo] = f2bf(oh);
            }
        }
    }
}

// ---------------------------------------------------------------------------
// decoder layer 1 (K=16, masked): r1b bf16 [256][512]
__global__ void k_dec1(const float* __restrict__ vsel, const int* __restrict__ label,
                       const void* __restrict__ w1, const void* __restrict__ b1,
                       unsigned short* __restrict__ r1b, const void* __restrict__ w1c) {
    int f = detect_f(w1c);
    int b = blockIdx.x, j = threadIdx.x;   // 512 threads
    __shared__ float vs[16];
    if (j < 16) vs[j] = vsel[b * 16 + j];
    __syncthreads();
    int lbl = label[b];
    size_t wb = (size_t)j * 160 + lbl * 16;
    float acc = rdf(b1, j, f);
#pragma unroll
    for (int n = 0; n < 16; ++n) acc += rdf(w1, wb + n, f) * vs[n];
    r1b[b * 512 + j] = f2bf(fmaxf(acc, 0.f));
}

// decoder GEMM: C[256,N] = A[256,K] x B[N,K]^T (+bias, act). 128x128 tiles.
__global__ __launch_bounds__(256) void k_dgemm(
        const unsigned short* __restrict__ A, const unsigned short* __restrict__ B,
        const void* __restrict__ bias, int K, int mode, int nvalid, int ostride,
        unsigned short* __restrict__ outb, void* __restrict__ d_out,
        const void* __restrict__ w1c) {
    int f = detect_f(w1c);
    int tid = threadIdx.x;
    int wave = tid >> 6, lane = tid & 63;
    int wr = wave >> 1, wc = wave & 1;
    int mbase = blockIdx.x * 128 + wr * 64;
    int nbase = blockIdx.y * 128 + wc * 64;
    int l15 = lane & 15, l4 = lane >> 4;
    int koff = l4 * 8;

    f32x4 acc[4][4];
#pragma unroll
    for (int mt = 0; mt < 4; ++mt)
#pragma unroll
        for (int nt = 0; nt < 4; ++nt)
            acc[mt][nt] = (f32x4){0.f, 0.f, 0.f, 0.f};

    int nch = K >> 5;
    for (int kc = 0; kc < nch; ++kc) {
        int k0 = kc * 32 + koff;
        short8 af[4], bfr[4];
#pragma unroll
        for (int mt = 0; mt < 4; ++mt)
            af[mt] = *(const short8*)(A + (size_t)(mbase + mt * 16 + l15) * K + k0);
#pragma unroll
        for (int nt = 0; nt < 4; ++nt)
            bfr[nt] = *(const short8*)(B + (size_t)(nbase + nt * 16 + l15) * K + k0);
#pragma unroll
        for (int mt = 0; mt < 4; ++mt)
#pragma unroll
            for (int nt = 0; nt < 4; ++nt)
                acc[mt][nt] = __builtin_amdgcn_mfma_f32_16x16x32_bf16(
                    af[mt], bfr[nt], acc[mt][nt], 0, 0, 0);
    }

#pragma unroll
    for (int mt = 0; mt < 4; ++mt)
#pragma unroll
        for (int nt = 0; nt < 4; ++nt) {
            int col = nbase + nt * 16 + l15;
            float bv = (col < nvalid) ? rdf(bias, col, f) : 0.f;
#pragma unroll
            for (int r = 0; r < 4; ++r) {
                int row = mbase + mt * 16 + l4 * 4 + r;
                float v = acc[mt][nt][r] + bv;
                if (mode == 0) {
                    outb[(size_t)row * ostride + col] = f2bf(fmaxf(v, 0.f));
                } else if (col < nvalid) {
                    float a = clampf(v, 60.f);
                    float sig = 1.f / (1.f + __expf(-a));
                    size_t oi = 40960 + (size_t)row * 784 + col;
                    if (f) ((float*)d_out)[oi] = sig;
                    else   ((unsigned short*)d_out)[oi] = f2bf(sig);
                }
            }
        }
}

// ---------------------------------------------------------------------------
extern "C" void kernel_launch(void* const* d_in, const int* in_sizes, int n_in,
                              void* d_out, int out_size, void* d_ws, size_t ws_size,
                              hipStream_t stream) {
    const void* x    = d_in[0];
    const int*  lbl  = (const int*)d_in[1];
    const void* w1c  = d_in[2];
    const void* b1c  = d_in[3];
    const void* w2c  = d_in[4];
    const void* b2c  = d_in[5];
    const void* wdig = d_in[6];
    const void* dw1  = d_in[7];
    const void* db1  = d_in[8];
    const void* dw2  = d_in[9];
    const void* db2  = d_in[10];
    const void* dw3  = d_in[11];
    const void* db3  = d_in[12];
    (void)in_sizes; (void)n_in; (void)out_size; (void)ws_size;

    char* ws = (char*)d_ws;
    // ---- layout, total 72,531,968 B (ws_size >= 74,123,264 known from R4) --
    float* h2f           = (float*)(ws);                      // 9,437,184
    unsigned short* Bp3  = (unsigned short*)(ws + 9437184);   // 10,616,832 [dead after conv2]
    unsigned short* caps = (unsigned short*)(ws + 9437184);   //   overlay: 4,718,592
    unsigned short* B1p  = (unsigned short*)(ws + 20054016);  // 49,152
    unsigned short* h1p  = (unsigned short*)(ws + 20103168);  // 52,428,800 [dead after conv2]
    //   overlays inside h1p region (written after conv2 by k_prep2 etc):
    unsigned short* Wdb2 = (unsigned short*)(ws + 20103168);  // 2,949,120
    unsigned short* w2b  = (unsigned short*)(ws + 23052288);  // 1,048,576
    unsigned short* w3b  = (unsigned short*)(ws + 24100864);  // 1,835,008
    unsigned short* r1b  = (unsigned short*)(ws + 25935872);  // 262,144
    unsigned short* r2b  = (unsigned short*)(ws + 26198016);  // 524,288
    float* vsel          = (float*)(ws + 26722304);           // 16,384

    hipLaunchKernelGGL(k_prep,  dim3(2656),     dim3(256), 0, stream, w1c, w2c, h2f, B1p, Bp3);
    hipLaunchKernelGGL(k_conv1, dim3(800, 2),   dim3(256), 0, stream, x, B1p, b1c, h1p, w1c);
    hipLaunchKernelGGL(k_conv2, dim3(72, 2, 8), dim3(256), 0, stream, h1p, Bp3, h2f);
    hipLaunchKernelGGL(k_prep2, dim3(5704),     dim3(256), 0, stream,
                       wdig, dw2, dw3, w1c, Wdb2, w2b, w3b);
    hipLaunchKernelGGL(k_caps2, dim3(256),      dim3(256), 0, stream, h2f, b2c, caps, w1c);
    hipLaunchKernelGGL(k_routing, dim3(2560),   dim3(384), 0, stream, caps, Wdb2, lbl,
                       d_out, vsel, w1c);
    hipLaunchKernelGGL(k_dec1,  dim3(256),      dim3(512), 0, stream, vsel, lbl, dw1, db1, r1b, w1c);
    hipLaunchKernelGGL(k_dgemm, dim3(2, 8),     dim3(256), 0, stream,
                       r1b, w2b, db2, 512, 0, 1024, 1024, r2b, d_out, w1c);
    hipLaunchKernelGGL(k_dgemm, dim3(2, 7),     dim3(256), 0, stream,
                       r2b, w3b, db3, 1024, 1, 784, 0, (unsigned short*)nullptr, d_out, w1c);
}